// Round 6
// baseline (3784.893 us; speedup 1.0000x reference)
//
#include <hip/hip_runtime.h>
#include <cstdint>
#include <cstddef>

#define B_GRAPHS 2048
#define N_NODES  64
#define FIN      49
#define D_DIM    256
#define H_HEADS  8
#define DK_DIM   32
#define L_LAYERS 6
#define ALPHA    0.2f

#define M_FULL     (B_GRAPHS * N_NODES)           // 131072 rows
#define WROWS      272                             // 256 W rows + 16 Wa rows
#define WSLAB      (WROWS * 256)                   // per-layer weight slab elems

typedef __bf16 bf16x8 __attribute__((ext_vector_type(8)));
typedef __bf16 bf16x4 __attribute__((ext_vector_type(4)));
typedef float  f32x4  __attribute__((ext_vector_type(4)));

#define MFMA16(a, b, c) __builtin_amdgcn_mfma_f32_16x16x32_bf16(a, b, c, 0, 0, 0)

__device__ __forceinline__ float leaky(float t) { return t > 0.f ? t : ALPHA * t; }

// ---------------------------------------------------------------------------
// Weight prep (round-5-verified): split W (+ Wa = W^T a rows) to bf16 hi/lo.
// ---------------------------------------------------------------------------
__global__ void convert_weights(const float* __restrict__ W_emb,
                                const float* __restrict__ gat_W,
                                const float* __restrict__ gat_a,
                                const float* __restrict__ gat_b,
                                __bf16* __restrict__ Whi_emb,
                                __bf16* __restrict__ Wlo_emb,
                                __bf16* __restrict__ Whi,
                                __bf16* __restrict__ Wlo,
                                float* __restrict__ ba)
{
    int idx = blockIdx.x * 256 + threadIdx.x;
    if (idx < 256 * 64) {
        int n = idx >> 6, k = idx & 63;
        float f = (k < FIN) ? W_emb[n * FIN + k] : 0.f;
        __bf16 hi = (__bf16)f;
        Whi_emb[idx] = hi;
        Wlo_emb[idx] = (__bf16)(f - (float)hi);
    }
    if (idx < L_LAYERS * 65536) {
        int l = idx >> 16, nk = idx & 65535;
        float f = gat_W[idx];
        __bf16 hi = (__bf16)f;
        int dst = l * WSLAB + nk;
        Whi[dst] = hi;
        Wlo[dst] = (__bf16)(f - (float)hi);
    }
    int o = idx - L_LAYERS * 65536;
    if (o >= 0 && o < L_LAYERS * 4096) {
        int l = o >> 12, r = o & 4095;
        int k = r >> 4, c = r & 15;
        int hh = c >> 1, sd = c & 1;
        const float* av = gat_a + l * 512 + hh * 64 + sd * 32;
        const float* wp = gat_W + ((size_t)l * 256 + hh * 32) * 256 + k;
        float s = 0.f;
        for (int d = 0; d < 32; d++) s += av[d] * wp[d * 256];
        int dst = l * WSLAB + (256 + c) * 256 + k;
        __bf16 hi = (__bf16)s;
        Whi[dst] = hi;
        Wlo[dst] = (__bf16)(s - (float)hi);
    }
    int o2 = idx - L_LAYERS * 65536 - L_LAYERS * 4096;
    if (o2 >= 0 && o2 < L_LAYERS * 16) {
        int l = o2 >> 4, c = o2 & 15;
        int hh = c >> 1, sd = c & 1;
        const float* av = gat_a + l * 512 + hh * 64 + sd * 32;
        const float* bp = gat_b + l * 256 + hh * 32;
        float s = 0.f;
        for (int d = 0; d < 32; d++) s += av[d] * bp[d];
        ba[o2] = s;
    }
}

// x [M][49] fp32 -> xhi/xlo [M][64] bf16 (zero-padded)
__global__ void convert_x(const float* __restrict__ x,
                          __bf16* __restrict__ xhi, __bf16* __restrict__ xlo)
{
    int idx = blockIdx.x * 256 + threadIdx.x;
    int m = idx >> 6, k = idx & 63;
    float f = (k < FIN) ? x[m * FIN + k] : 0.f;
    __bf16 hi = (__bf16)f;
    xhi[idx] = hi;
    xlo[idx] = (__bf16)(f - (float)hi);
}

// ---------------------------------------------------------------------------
// Adjacency bitmasks, once: masks[g][r] bit j = A[g][r][j] > 0.
// ---------------------------------------------------------------------------
__global__ void build_masks(const float* __restrict__ A,
                            unsigned long long* __restrict__ masks)
{
    int g = blockIdx.x;
    int lane = threadIdx.x & 63;
    int w = threadIdx.x >> 6;
    const float* Ab = A + (size_t)g * 4096;
    for (int rr = 0; rr < 16; rr++) {
        int r = w * 16 + rr;
        unsigned long long m = __ballot(Ab[r * 64 + lane] > 0.f);
        if (lane == 0) masks[g * 64 + r] = m;
    }
}

// ---------------------------------------------------------------------------
// Embed GEMM: hhi/hlo[M,256] = split(x @ W_emb^T), 3-term bf16 MFMA.
// ---------------------------------------------------------------------------
__device__ __forceinline__ int swz(int r, int s) {
    return r * 64 + (((s ^ (r & 3)) << 4));
}

__global__ __launch_bounds__(256, 2)
void gemm_embed(const __bf16* __restrict__ Ahi, const __bf16* __restrict__ Alo,
                const __bf16* __restrict__ Bhi, const __bf16* __restrict__ Blo,
                __bf16* __restrict__ Chi, __bf16* __restrict__ Clo)
{
    const int K = 64;
    __shared__ __align__(16) char lds[2][32768];

    const int tid  = threadIdx.x;
    const int m0   = blockIdx.x * 128;
    const int n0   = blockIdx.y * 128;
    const int lane = tid & 63;
    const int wid  = tid >> 6;
    const int wr   = wid >> 1, wc = wid & 1;

    bf16x8 regAh[2], regAl[2], regBh[2], regBl[2];
    f32x4 acc[4][4];
#pragma unroll
    for (int i = 0; i < 4; i++)
#pragma unroll
        for (int j = 0; j < 4; j++) acc[i][j] = (f32x4){0.f, 0.f, 0.f, 0.f};

    auto load_stage = [&](int k0) {
#pragma unroll
        for (int g = 0; g < 2; g++) {
            int u = g * 256 + tid, r = u >> 2, s = u & 3;
            regAh[g] = *(const bf16x8*)(Ahi + (size_t)(m0 + r) * K + k0 + s * 8);
            regAl[g] = *(const bf16x8*)(Alo + (size_t)(m0 + r) * K + k0 + s * 8);
            regBh[g] = *(const bf16x8*)(Bhi + (size_t)(n0 + r) * K + k0 + s * 8);
            regBl[g] = *(const bf16x8*)(Blo + (size_t)(n0 + r) * K + k0 + s * 8);
        }
    };
    auto write_stage = [&](int buf) {
        char* base = lds[buf];
#pragma unroll
        for (int g = 0; g < 2; g++) {
            int u = g * 256 + tid, r = u >> 2, s = u & 3;
            int off = swz(r, s);
            *(bf16x8*)(base + off)         = regAh[g];
            *(bf16x8*)(base + 8192 + off)  = regAl[g];
            *(bf16x8*)(base + 16384 + off) = regBh[g];
            *(bf16x8*)(base + 24576 + off) = regBl[g];
        }
    };
    auto compute = [&](int buf) {
        const char* base = lds[buf];
        const int s = lane >> 4;
        bf16x8 ah[4], al[4];
#pragma unroll
        for (int mf = 0; mf < 4; mf++) {
            int r = wr * 64 + mf * 16 + (lane & 15);
            int off = swz(r, s);
            ah[mf] = *(const bf16x8*)(base + off);
            al[mf] = *(const bf16x8*)(base + 8192 + off);
        }
#pragma unroll
        for (int nf = 0; nf < 4; nf++) {
            int r = wc * 64 + nf * 16 + (lane & 15);
            int off = swz(r, s);
            bf16x8 bh = *(const bf16x8*)(base + 16384 + off);
            bf16x8 bl = *(const bf16x8*)(base + 24576 + off);
#pragma unroll
            for (int mf = 0; mf < 4; mf++) {
                acc[mf][nf] = MFMA16(ah[mf], bh, acc[mf][nf]);
                acc[mf][nf] = MFMA16(ah[mf], bl, acc[mf][nf]);
                acc[mf][nf] = MFMA16(al[mf], bh, acc[mf][nf]);
            }
        }
    };

    load_stage(0);
    write_stage(0);
    load_stage(32);
    __syncthreads();
    compute(0);
    write_stage(1);
    __syncthreads();
    compute(1);

#pragma unroll
    for (int nf = 0; nf < 4; nf++) {
        int col = n0 + wc * 64 + nf * 16 + (lane & 15);
#pragma unroll
        for (int mf = 0; mf < 4; mf++) {
            int rbase = m0 + wr * 64 + mf * 16 + (lane >> 4) * 4;
#pragma unroll
            for (int rr = 0; rr < 4; rr++) {
                size_t idx = (size_t)(rbase + rr) * 256 + col;
                float v = acc[mf][nf][rr];
                __bf16 hb = (__bf16)v;
                Chi[idx] = hb;
                Clo[idx] = (__bf16)(v - (float)hb);
            }
        }
    }
}

// ---------------------------------------------------------------------------
// Fused GAT layer v3: one graph/block, 4 waves, wave owns 64 cols = 2 heads
// processed sequentially (halves LDS -> 4 blocks/CU). h stored as bf16 hi/lo:
// A-frags are direct loads, residual = hi+lo, epilogue re-splits.
// Per-wave LDS (9472 B): Vhi@0 (4K) Vlo@4096 (4K) E@8192 (1K) inv@9216 (256).
// ONE barrier (WAR: all A-reads of h before any epilogue h-write).
// ---------------------------------------------------------------------------
__global__ __launch_bounds__(256, 4)
void fused_gat_layer(const unsigned long long* __restrict__ masks,
                     __bf16* hhi, __bf16* hlo,
                     const __bf16* __restrict__ Whi, const __bf16* __restrict__ Wlo,
                     const float* __restrict__ bias,
                     const float* __restrict__ ba)
{
    __shared__ __align__(16) char smem[4 * 9472];

    const int tid  = threadIdx.x;
    const int lane = tid & 63;
    const int w    = tid >> 6;
    const int q    = lane >> 4;
    const int d15  = lane & 15;
    const int g    = blockIdx.x;
    const size_t m0 = (size_t)g * 64;

    char*  wbase = smem + w * 9472;
    float* E     = (float*)(wbase + 8192);
    float* invv  = (float*)(wbase + 9216);

    // --- GEMM: acc[mf][nf] = hp tile (this wave's 64 cols), accE = es/ed ---
    f32x4 acc[4][4], accE[4];
#pragma unroll
    for (int i = 0; i < 4; i++) {
        accE[i] = (f32x4){0.f, 0.f, 0.f, 0.f};
#pragma unroll
        for (int j = 0; j < 4; j++) acc[i][j] = (f32x4){0.f, 0.f, 0.f, 0.f};
    }

#pragma unroll 2
    for (int ks = 0; ks < 8; ks++) {
        const int k0 = ks * 32 + q * 8;
        bf16x8 ah[4], al[4];
#pragma unroll
        for (int mf = 0; mf < 4; mf++) {
            ah[mf] = *(const bf16x8*)(hhi + (m0 + mf * 16 + d15) * 256 + k0);
            al[mf] = *(const bf16x8*)(hlo + (m0 + mf * 16 + d15) * 256 + k0);
        }
#pragma unroll
        for (int nt = 0; nt < 5; nt++) {
            int n = (nt < 4) ? (w * 64 + nt * 16 + d15) : (256 + d15);
            bf16x8 bh = *(const bf16x8*)(Whi + (size_t)n * 256 + k0);
            bf16x8 bl = *(const bf16x8*)(Wlo + (size_t)n * 256 + k0);
            if (nt < 4) {
#pragma unroll
                for (int mf = 0; mf < 4; mf++) {
                    acc[mf][nt] = MFMA16(ah[mf], bh, acc[mf][nt]);
                    acc[mf][nt] = MFMA16(ah[mf], bl, acc[mf][nt]);
                    acc[mf][nt] = MFMA16(al[mf], bh, acc[mf][nt]);
                }
            } else {
#pragma unroll
                for (int mf = 0; mf < 4; mf++) {
                    accE[mf] = MFMA16(ah[mf], bh, accE[mf]);
                    accE[mf] = MFMA16(ah[mf], bl, accE[mf]);
                    accE[mf] = MFMA16(al[mf], bh, accE[mf]);
                }
            }
        }
    }

    // All h A-reads complete before any epilogue h-write (only barrier).
    __syncthreads();

    // --- adjacency masks (post-GEMM to keep GEMM-phase registers lean) ---
    unsigned long long msk[4];
#pragma unroll
    for (int mf = 0; mf < 4; mf++) msk[mf] = masks[g * 64 + mf * 16 + d15];

    // --- E (es/ed for this wave's heads): cols 4w..4w+3 ---
    if (d15 >= 4 * w && d15 < 4 * w + 4) {
        const int cl = d15 - 4 * w;
        const float bav = ba[d15];
#pragma unroll
        for (int mf = 0; mf < 4; mf++)
#pragma unroll
            for (int rr = 0; rr < 4; rr++)
                E[cl * 64 + mf * 16 + q * 4 + rr] = accE[mf][rr] + bav;
    }

    // --- per-head: write V frags -> in-register P synth -> PV MFMA -> store ---
#pragma unroll
    for (int hl = 0; hl < 2; hl++) {
        const int head = 2 * w + hl;

        // V fragments for this head (wave-private, swizzled [d][j] hi/lo)
#pragma unroll
        for (int nfl = 0; nfl < 2; nfl++) {
            const int nf = hl * 2 + nfl;
            const int d  = nfl * 16 + d15;
            const float bv = bias[w * 64 + nf * 16 + d15];
            char* vb = wbase + d * 128;
#pragma unroll
            for (int mf = 0; mf < 4; mf++) {
                int s   = mf * 2 + (q >> 1);
                int off = ((s ^ (d & 7)) << 4) + (q & 1) * 8;
                bf16x4 h4, l4;
#pragma unroll
                for (int rr = 0; rr < 4; rr++) {
                    float v = acc[mf][nf][rr] + bv;
                    __bf16 hb = (__bf16)v;
                    h4[rr] = hb;
                    l4[rr] = (__bf16)(v - (float)hb);
                }
                *(bf16x4*)(vb + off)        = h4;
                *(bf16x4*)(vb + 4096 + off) = l4;
            }
        }

        float ev = E[(hl * 2 + 1) * 64 + lane];
#pragma unroll
        for (int off = 32; off; off >>= 1) ev = fmaxf(ev, __shfl_xor(ev, off));

        float esi[4], mh[4];
#pragma unroll
        for (int mf = 0; mf < 4; mf++) {
            esi[mf] = E[(hl * 2) * 64 + mf * 16 + d15];
            mh[mf]  = leaky(esi[mf] + ev);
        }

        f32x4 pv[4][2];
#pragma unroll
        for (int mf = 0; mf < 4; mf++) {
            pv[mf][0] = (f32x4){0.f, 0.f, 0.f, 0.f};
            pv[mf][1] = (f32x4){0.f, 0.f, 0.f, 0.f};
        }
        float rs[4] = {0.f, 0.f, 0.f, 0.f};

#pragma unroll
        for (int ksj = 0; ksj < 2; ksj++) {
            const int j8 = ksj * 32 + q * 8;
            const int s  = ksj * 4 + q;
            bf16x8 vh[2], vl[2];
#pragma unroll
            for (int nf2 = 0; nf2 < 2; nf2++) {
                int d = nf2 * 16 + d15;
                int off = d * 128 + ((s ^ (d & 7)) << 4);
                vh[nf2] = *(const bf16x8*)(wbase + off);
                vl[nf2] = *(const bf16x8*)(wbase + 4096 + off);
            }
            float edv[8];
#pragma unroll
            for (int e = 0; e < 8; e++) edv[e] = E[(hl * 2 + 1) * 64 + j8 + e];

#pragma unroll
            for (int mf = 0; mf < 4; mf++) {
                unsigned int mb = (unsigned int)(msk[mf] >> j8) & 0xffu;
                bf16x8 ph, pl;
                float rsum = 0.f;
#pragma unroll
                for (int e = 0; e < 8; e++) {
                    float t = leaky(esi[mf] + edv[e]);
                    float p = ((mb >> e) & 1u) ? __expf(t - mh[mf]) : 0.f;
                    rsum += p;
                    __bf16 hb = (__bf16)p;
                    ph[e] = hb;
                    pl[e] = (__bf16)(p - (float)hb);
                }
                rs[mf] += rsum;
#pragma unroll
                for (int nf2 = 0; nf2 < 2; nf2++) {
                    pv[mf][nf2] = MFMA16(ph, vh[nf2], pv[mf][nf2]);
                    pv[mf][nf2] = MFMA16(ph, vl[nf2], pv[mf][nf2]);
                    pv[mf][nf2] = MFMA16(pl, vh[nf2], pv[mf][nf2]);
                }
            }
        }

        // row sums -> 1/s
#pragma unroll
        for (int mf = 0; mf < 4; mf++) {
            float r = rs[mf];
            r += __shfl_xor(r, 16);
            r += __shfl_xor(r, 32);
            if (q == 0) invv[mf * 16 + d15] = (r > 0.f) ? 1.f / r : 0.f;
        }

        // epilogue: scale, residual (hi+lo), ELU, re-split store
#pragma unroll
        for (int mf = 0; mf < 4; mf++) {
#pragma unroll
            for (int nf2 = 0; nf2 < 2; nf2++) {
                int d = head * 32 + nf2 * 16 + d15;
#pragma unroll
                for (int rr = 0; rr < 4; rr++) {
                    int i = mf * 16 + q * 4 + rr;
                    float inv = invv[i];
                    size_t idx = (m0 + i) * 256 + d;
                    float old = (float)hhi[idx] + (float)hlo[idx];
                    float o = pv[mf][nf2][rr] * inv + old;
                    o = o > 0.f ? o : __expf(o) - 1.f;
                    __bf16 hb = (__bf16)o;
                    hhi[idx] = hb;
                    hlo[idx] = (__bf16)(o - (float)hb);
                }
            }
        }
    }
}

// ---------------------------------------------------------------------------
// Masked mean-pool + 3-layer MLP + elu + 1.5. One block per graph.
// ---------------------------------------------------------------------------
__global__ __launch_bounds__(256)
void pool_mlp(const unsigned long long* __restrict__ masks,
              const __bf16* __restrict__ hhi, const __bf16* __restrict__ hlo,
              const float* __restrict__ W1, const float* __restrict__ b1,
              const float* __restrict__ W2, const float* __restrict__ b2,
              const float* __restrict__ W3, const float* __restrict__ b3,
              float* __restrict__ out)
{
    __shared__ float lds_g[256];
    __shared__ float lds_z1[128];
    __shared__ float lds_z2[128];
    __shared__ unsigned long long lds_m;
    __shared__ float lds_invcnt;

    const int tid = threadIdx.x;
    const int b   = blockIdx.x;
    const __bf16* hbh = hhi + (size_t)b * 16384;
    const __bf16* hbl = hlo + (size_t)b * 16384;

    if (tid < 64) {
        unsigned long long rowm = masks[b * 64 + tid];
        unsigned long long m = __ballot((rowm >> tid) & 1ULL);
        if (tid == 0) { lds_m = m; lds_invcnt = 1.f / (float)__popcll(m); }
    }
    __syncthreads();

    unsigned long long msk = lds_m;
    float invc = lds_invcnt;
    float gsum = 0.f;
    for (int n = 0; n < 64; n++)
        if ((msk >> n) & 1ULL)
            gsum += (float)hbh[n * 256 + tid] + (float)hbl[n * 256 + tid];
    lds_g[tid] = gsum * invc;
    __syncthreads();

    if (tid < 128) {
        const float* wr = W1 + tid * 256;
        float z = 0.f;
#pragma unroll 8
        for (int k = 0; k < 256; k += 4) {
            float4 wv = *(const float4*)&wr[k];
            z += wv.x * lds_g[k] + wv.y * lds_g[k + 1] + wv.z * lds_g[k + 2] + wv.w * lds_g[k + 3];
        }
        z += b1[tid];
        lds_z1[tid] = z > 0.f ? z : 0.f;
    }
    __syncthreads();

    if (tid < 128) {
        const float* wr = W2 + tid * 128;
        float z = 0.f;
#pragma unroll 8
        for (int k = 0; k < 128; k += 4) {
            float4 wv = *(const float4*)&wr[k];
            z += wv.x * lds_z1[k] + wv.y * lds_z1[k + 1] + wv.z * lds_z1[k + 2] + wv.w * lds_z1[k + 3];
        }
        z += b2[tid];
        lds_z2[tid] = z > 0.f ? z : 0.f;
    }
    __syncthreads();

    if (tid < 64) {
        float p = W3[tid] * lds_z2[tid] + W3[tid + 64] * lds_z2[tid + 64];
        for (int off = 32; off; off >>= 1) p += __shfl_down(p, off);
        if (tid == 0) {
            float z = p + b3[0];
            out[b] = (z > 0.f ? z : __expf(z) - 1.f) + 1.5f;
        }
    }
}

// ---------------------------------------------------------------------------
extern "C" void kernel_launch(void* const* d_in, const int* in_sizes, int n_in,
                              void* d_out, int out_size, void* d_ws, size_t ws_size,
                              hipStream_t stream)
{
    const float* x      = (const float*)d_in[0];
    const float* A      = (const float*)d_in[1];
    const float* W_emb  = (const float*)d_in[2];
    const float* gat_W  = (const float*)d_in[3];
    const float* gat_b  = (const float*)d_in[4];
    const float* gat_a  = (const float*)d_in[5];
    const float* fc_W1  = (const float*)d_in[6];
    const float* fc_b1  = (const float*)d_in[7];
    const float* fc_W2  = (const float*)d_in[8];
    const float* fc_b2  = (const float*)d_in[9];
    const float* fc_W3  = (const float*)d_in[10];
    const float* fc_b3  = (const float*)d_in[11];
    float* out = (float*)d_out;

    // workspace (~105 MB):
    //   hhi bf16 [131072][256]      @ 0            67108864
    //   hlo bf16 [131072][256]      @ 67108864     67108864   -> 134217728
    //   xhi/xlo bf16 [131072][64]   @ 134217728    2 x 16777216
    //   Whi_emb/Wlo_emb [256][64]   @ 167772160    2 x 32768
    //   Whi [6][272][256] bf16      @ 167837696    835584
    //   Wlo                         @ 168673280    835584
    //   ba  [6][16] f32             @ 169508864    384
    //   masks u64 [2048][64]        @ 169510912    1048576
    char* ws = (char*)d_ws;
    __bf16* hhi     = (__bf16*)ws;
    __bf16* hlo     = (__bf16*)(ws + 67108864);
    __bf16* xhi     = (__bf16*)(ws + 134217728);
    __bf16* xlo     = (__bf16*)(ws + 134217728 + 16777216);
    __bf16* Whi_emb = (__bf16*)(ws + 167772160);
    __bf16* Wlo_emb = (__bf16*)(ws + 167772160 + 32768);
    __bf16* Whi     = (__bf16*)(ws + 167837696);
    __bf16* Wlo     = (__bf16*)(ws + 168673280);
    float*  ba      = (float*)(ws + 169508864);
    unsigned long long* masks = (unsigned long long*)(ws + 169510912);

    int conv_total = L_LAYERS * 65536 + L_LAYERS * 4096 + L_LAYERS * 16;
    convert_weights<<<(conv_total + 255) / 256, 256, 0, stream>>>(
        W_emb, gat_W, gat_a, gat_b, Whi_emb, Wlo_emb, Whi, Wlo, ba);
    convert_x<<<M_FULL * 64 / 256, 256, 0, stream>>>(x, xhi, xlo);
    build_masks<<<B_GRAPHS, 256, 0, stream>>>(A, masks);

    gemm_embed<<<dim3(M_FULL / 128, 2), 256, 0, stream>>>(
        xhi, xlo, Whi_emb, Wlo_emb, hhi, hlo);

    for (int l = 0; l < L_LAYERS; l++) {
        fused_gat_layer<<<B_GRAPHS, 256, 0, stream>>>(
            masks, hhi, hlo,
            Whi + (size_t)l * WSLAB, Wlo + (size_t)l * WSLAB,
            gat_b + l * D_DIM, ba + l * 16);
    }

    pool_mlp<<<B_GRAPHS, 256, 0, stream>>>(masks, hhi, hlo, fc_W1, fc_b1,
                                           fc_W2, fc_b2, fc_W3, fc_b3, out);
}

// Round 7
// 1550.406 us; speedup vs baseline: 2.4412x; 2.4412x over previous
//
#include <hip/hip_runtime.h>
#include <cstdint>
#include <cstddef>

#define B_GRAPHS 2048
#define N_NODES  64
#define FIN      49
#define D_DIM    256
#define H_HEADS  8
#define DK_DIM   32
#define L_LAYERS 6
#define ALPHA    0.2f

#define M_FULL     (B_GRAPHS * N_NODES)           // 131072 rows
#define WROWS      272                             // 256 W rows + 16 Wa rows
#define WSLAB      (WROWS * 256)                   // per-layer weight slab elems

typedef __bf16 bf16x8 __attribute__((ext_vector_type(8)));
typedef __bf16 bf16x4 __attribute__((ext_vector_type(4)));
typedef float  f32x4  __attribute__((ext_vector_type(4)));

#define MFMA16(a, b, c) __builtin_amdgcn_mfma_f32_16x16x32_bf16(a, b, c, 0, 0, 0)

__device__ __forceinline__ float leaky(float t) { return t > 0.f ? t : ALPHA * t; }

// ---------------------------------------------------------------------------
// Weight prep (round-5-verified): split W (+ Wa = W^T a rows) to bf16 hi/lo.
// ---------------------------------------------------------------------------
__global__ void convert_weights(const float* __restrict__ W_emb,
                                const float* __restrict__ gat_W,
                                const float* __restrict__ gat_a,
                                const float* __restrict__ gat_b,
                                __bf16* __restrict__ Whi_emb,
                                __bf16* __restrict__ Wlo_emb,
                                __bf16* __restrict__ Whi,
                                __bf16* __restrict__ Wlo,
                                float* __restrict__ ba)
{
    int idx = blockIdx.x * 256 + threadIdx.x;
    if (idx < 256 * 64) {
        int n = idx >> 6, k = idx & 63;
        float f = (k < FIN) ? W_emb[n * FIN + k] : 0.f;
        __bf16 hi = (__bf16)f;
        Whi_emb[idx] = hi;
        Wlo_emb[idx] = (__bf16)(f - (float)hi);
    }
    if (idx < L_LAYERS * 65536) {
        int l = idx >> 16, nk = idx & 65535;
        float f = gat_W[idx];
        __bf16 hi = (__bf16)f;
        int dst = l * WSLAB + nk;
        Whi[dst] = hi;
        Wlo[dst] = (__bf16)(f - (float)hi);
    }
    int o = idx - L_LAYERS * 65536;
    if (o >= 0 && o < L_LAYERS * 4096) {
        int l = o >> 12, r = o & 4095;
        int k = r >> 4, c = r & 15;
        int hh = c >> 1, sd = c & 1;
        const float* av = gat_a + l * 512 + hh * 64 + sd * 32;
        const float* wp = gat_W + ((size_t)l * 256 + hh * 32) * 256 + k;
        float s = 0.f;
        for (int d = 0; d < 32; d++) s += av[d] * wp[d * 256];
        int dst = l * WSLAB + (256 + c) * 256 + k;
        __bf16 hi = (__bf16)s;
        Whi[dst] = hi;
        Wlo[dst] = (__bf16)(s - (float)hi);
    }
    int o2 = idx - L_LAYERS * 65536 - L_LAYERS * 4096;
    if (o2 >= 0 && o2 < L_LAYERS * 16) {
        int l = o2 >> 4, c = o2 & 15;
        int hh = c >> 1, sd = c & 1;
        const float* av = gat_a + l * 512 + hh * 64 + sd * 32;
        const float* bp = gat_b + l * 256 + hh * 32;
        float s = 0.f;
        for (int d = 0; d < 32; d++) s += av[d] * bp[d];
        ba[o2] = s;
    }
}

// x [M][49] fp32 -> xhi/xlo [M][64] bf16 (zero-padded)
__global__ void convert_x(const float* __restrict__ x,
                          __bf16* __restrict__ xhi, __bf16* __restrict__ xlo)
{
    int idx = blockIdx.x * 256 + threadIdx.x;
    int m = idx >> 6, k = idx & 63;
    float f = (k < FIN) ? x[m * FIN + k] : 0.f;
    __bf16 hi = (__bf16)f;
    xhi[idx] = hi;
    xlo[idx] = (__bf16)(f - (float)hi);
}

// ---------------------------------------------------------------------------
// Adjacency bitmasks, once: masks[g][r] bit j = A[g][r][j] > 0.
// ---------------------------------------------------------------------------
__global__ void build_masks(const float* __restrict__ A,
                            unsigned long long* __restrict__ masks)
{
    int g = blockIdx.x;
    int lane = threadIdx.x & 63;
    int w = threadIdx.x >> 6;
    const float* Ab = A + (size_t)g * 4096;
    for (int rr = 0; rr < 16; rr++) {
        int r = w * 16 + rr;
        unsigned long long m = __ballot(Ab[r * 64 + lane] > 0.f);
        if (lane == 0) masks[g * 64 + r] = m;
    }
}

// ---------------------------------------------------------------------------
// Embed GEMM: hhi/hlo[M,256] = split(x @ W_emb^T), 3-term bf16 MFMA.
// ---------------------------------------------------------------------------
__device__ __forceinline__ int swz(int r, int s) {
    return r * 64 + (((s ^ (r & 3)) << 4));
}

__global__ __launch_bounds__(256, 2)
void gemm_embed(const __bf16* __restrict__ Ahi, const __bf16* __restrict__ Alo,
                const __bf16* __restrict__ Bhi, const __bf16* __restrict__ Blo,
                __bf16* __restrict__ Chi, __bf16* __restrict__ Clo)
{
    const int K = 64;
    __shared__ __align__(16) char lds[2][32768];

    const int tid  = threadIdx.x;
    const int m0   = blockIdx.x * 128;
    const int n0   = blockIdx.y * 128;
    const int lane = tid & 63;
    const int wid  = tid >> 6;
    const int wr   = wid >> 1, wc = wid & 1;

    bf16x8 regAh[2], regAl[2], regBh[2], regBl[2];
    f32x4 acc[4][4];
#pragma unroll
    for (int i = 0; i < 4; i++)
#pragma unroll
        for (int j = 0; j < 4; j++) acc[i][j] = (f32x4){0.f, 0.f, 0.f, 0.f};

    auto load_stage = [&](int k0) {
#pragma unroll
        for (int g = 0; g < 2; g++) {
            int u = g * 256 + tid, r = u >> 2, s = u & 3;
            regAh[g] = *(const bf16x8*)(Ahi + (size_t)(m0 + r) * K + k0 + s * 8);
            regAl[g] = *(const bf16x8*)(Alo + (size_t)(m0 + r) * K + k0 + s * 8);
            regBh[g] = *(const bf16x8*)(Bhi + (size_t)(n0 + r) * K + k0 + s * 8);
            regBl[g] = *(const bf16x8*)(Blo + (size_t)(n0 + r) * K + k0 + s * 8);
        }
    };
    auto write_stage = [&](int buf) {
        char* base = lds[buf];
#pragma unroll
        for (int g = 0; g < 2; g++) {
            int u = g * 256 + tid, r = u >> 2, s = u & 3;
            int off = swz(r, s);
            *(bf16x8*)(base + off)         = regAh[g];
            *(bf16x8*)(base + 8192 + off)  = regAl[g];
            *(bf16x8*)(base + 16384 + off) = regBh[g];
            *(bf16x8*)(base + 24576 + off) = regBl[g];
        }
    };
    auto compute = [&](int buf) {
        const char* base = lds[buf];
        const int s = lane >> 4;
        bf16x8 ah[4], al[4];
#pragma unroll
        for (int mf = 0; mf < 4; mf++) {
            int r = wr * 64 + mf * 16 + (lane & 15);
            int off = swz(r, s);
            ah[mf] = *(const bf16x8*)(base + off);
            al[mf] = *(const bf16x8*)(base + 8192 + off);
        }
#pragma unroll
        for (int nf = 0; nf < 4; nf++) {
            int r = wc * 64 + nf * 16 + (lane & 15);
            int off = swz(r, s);
            bf16x8 bh = *(const bf16x8*)(base + 16384 + off);
            bf16x8 bl = *(const bf16x8*)(base + 24576 + off);
#pragma unroll
            for (int mf = 0; mf < 4; mf++) {
                acc[mf][nf] = MFMA16(ah[mf], bh, acc[mf][nf]);
                acc[mf][nf] = MFMA16(ah[mf], bl, acc[mf][nf]);
                acc[mf][nf] = MFMA16(al[mf], bh, acc[mf][nf]);
            }
        }
    };

    load_stage(0);
    write_stage(0);
    load_stage(32);
    __syncthreads();
    compute(0);
    write_stage(1);
    __syncthreads();
    compute(1);

#pragma unroll
    for (int nf = 0; nf < 4; nf++) {
        int col = n0 + wc * 64 + nf * 16 + (lane & 15);
#pragma unroll
        for (int mf = 0; mf < 4; mf++) {
            int rbase = m0 + wr * 64 + mf * 16 + (lane >> 4) * 4;
#pragma unroll
            for (int rr = 0; rr < 4; rr++) {
                size_t idx = (size_t)(rbase + rr) * 256 + col;
                float v = acc[mf][nf][rr];
                __bf16 hb = (__bf16)v;
                Chi[idx] = hb;
                Clo[idx] = (__bf16)(v - (float)hb);
            }
        }
    }
}

// ---------------------------------------------------------------------------
// Fused GAT layer v3b: one graph/block, 4 waves, wave owns 64 cols = 2 heads
// sequentially. h stored bf16 hi/lo (direct A-frag loads, no conversions).
// __launch_bounds__(256,2): compiler allocates ~104 VGPR (<=128), so HW still
// runs 4 blocks/CU (LDS 37888) = 16 waves/CU. Round-6's (256,4) capped VGPR
// at 64 -> scratch spill -> 2 GB/dispatch HBM traffic. Do not reintroduce.
// Per-wave LDS (9472 B): Vhi@0 (4K) Vlo@4096 (4K) E@8192 (1K) inv@9216 (256).
// ONE barrier (WAR: all A-reads of h before any epilogue h-write).
// ---------------------------------------------------------------------------
__global__ __launch_bounds__(256, 2)
void fused_gat_layer(const unsigned long long* __restrict__ masks,
                     __bf16* hhi, __bf16* hlo,
                     const __bf16* __restrict__ Whi, const __bf16* __restrict__ Wlo,
                     const float* __restrict__ bias,
                     const float* __restrict__ ba)
{
    __shared__ __align__(16) char smem[4 * 9472];

    const int tid  = threadIdx.x;
    const int lane = tid & 63;
    const int w    = tid >> 6;
    const int q    = lane >> 4;
    const int d15  = lane & 15;
    const int g    = blockIdx.x;
    const size_t m0 = (size_t)g * 64;

    char*  wbase = smem + w * 9472;
    float* E     = (float*)(wbase + 8192);
    float* invv  = (float*)(wbase + 9216);

    // --- GEMM: acc[mf][nf] = hp tile (this wave's 64 cols), accE = es/ed ---
    f32x4 acc[4][4], accE[4];
#pragma unroll
    for (int i = 0; i < 4; i++) {
        accE[i] = (f32x4){0.f, 0.f, 0.f, 0.f};
#pragma unroll
        for (int j = 0; j < 4; j++) acc[i][j] = (f32x4){0.f, 0.f, 0.f, 0.f};
    }

#pragma unroll 2
    for (int ks = 0; ks < 8; ks++) {
        const int k0 = ks * 32 + q * 8;
        bf16x8 ah[4], al[4];
#pragma unroll
        for (int mf = 0; mf < 4; mf++) {
            ah[mf] = *(const bf16x8*)(hhi + (m0 + mf * 16 + d15) * 256 + k0);
            al[mf] = *(const bf16x8*)(hlo + (m0 + mf * 16 + d15) * 256 + k0);
        }
#pragma unroll
        for (int nt = 0; nt < 5; nt++) {
            int n = (nt < 4) ? (w * 64 + nt * 16 + d15) : (256 + d15);
            bf16x8 bh = *(const bf16x8*)(Whi + (size_t)n * 256 + k0);
            bf16x8 bl = *(const bf16x8*)(Wlo + (size_t)n * 256 + k0);
            if (nt < 4) {
#pragma unroll
                for (int mf = 0; mf < 4; mf++) {
                    acc[mf][nt] = MFMA16(ah[mf], bh, acc[mf][nt]);
                    acc[mf][nt] = MFMA16(ah[mf], bl, acc[mf][nt]);
                    acc[mf][nt] = MFMA16(al[mf], bh, acc[mf][nt]);
                }
            } else {
#pragma unroll
                for (int mf = 0; mf < 4; mf++) {
                    accE[mf] = MFMA16(ah[mf], bh, accE[mf]);
                    accE[mf] = MFMA16(ah[mf], bl, accE[mf]);
                    accE[mf] = MFMA16(al[mf], bh, accE[mf]);
                }
            }
        }
    }

    // All h A-reads complete before any epilogue h-write (only barrier).
    __syncthreads();

    // --- adjacency masks ---
    unsigned long long msk[4];
#pragma unroll
    for (int mf = 0; mf < 4; mf++) msk[mf] = masks[g * 64 + mf * 16 + d15];

    // --- E (es/ed for this wave's heads): cols 4w..4w+3 ---
    if (d15 >= 4 * w && d15 < 4 * w + 4) {
        const int cl = d15 - 4 * w;
        const float bav = ba[d15];
#pragma unroll
        for (int mf = 0; mf < 4; mf++)
#pragma unroll
            for (int rr = 0; rr < 4; rr++)
                E[cl * 64 + mf * 16 + q * 4 + rr] = accE[mf][rr] + bav;
    }

    // --- per-head: write V frags -> in-register P synth -> PV MFMA -> store ---
#pragma unroll
    for (int hl = 0; hl < 2; hl++) {
        const int head = 2 * w + hl;

        // V fragments for this head (wave-private, swizzled [d][j] hi/lo)
#pragma unroll
        for (int nfl = 0; nfl < 2; nfl++) {
            const int nf = hl * 2 + nfl;
            const int d  = nfl * 16 + d15;
            const float bv = bias[w * 64 + nf * 16 + d15];
            char* vb = wbase + d * 128;
#pragma unroll
            for (int mf = 0; mf < 4; mf++) {
                int s   = mf * 2 + (q >> 1);
                int off = ((s ^ (d & 7)) << 4) + (q & 1) * 8;
                bf16x4 h4, l4;
#pragma unroll
                for (int rr = 0; rr < 4; rr++) {
                    float v = acc[mf][nf][rr] + bv;
                    __bf16 hb = (__bf16)v;
                    h4[rr] = hb;
                    l4[rr] = (__bf16)(v - (float)hb);
                }
                *(bf16x4*)(vb + off)        = h4;
                *(bf16x4*)(vb + 4096 + off) = l4;
            }
        }

        float ev = E[(hl * 2 + 1) * 64 + lane];
#pragma unroll
        for (int off = 32; off; off >>= 1) ev = fmaxf(ev, __shfl_xor(ev, off));

        float esi[4], mh[4];
#pragma unroll
        for (int mf = 0; mf < 4; mf++) {
            esi[mf] = E[(hl * 2) * 64 + mf * 16 + d15];
            mh[mf]  = leaky(esi[mf] + ev);
        }

        f32x4 pv[4][2];
#pragma unroll
        for (int mf = 0; mf < 4; mf++) {
            pv[mf][0] = (f32x4){0.f, 0.f, 0.f, 0.f};
            pv[mf][1] = (f32x4){0.f, 0.f, 0.f, 0.f};
        }
        float rs[4] = {0.f, 0.f, 0.f, 0.f};

#pragma unroll
        for (int ksj = 0; ksj < 2; ksj++) {
            const int j8 = ksj * 32 + q * 8;
            const int s  = ksj * 4 + q;
            bf16x8 vh[2], vl[2];
#pragma unroll
            for (int nf2 = 0; nf2 < 2; nf2++) {
                int d = nf2 * 16 + d15;
                int off = d * 128 + ((s ^ (d & 7)) << 4);
                vh[nf2] = *(const bf16x8*)(wbase + off);
                vl[nf2] = *(const bf16x8*)(wbase + 4096 + off);
            }
            float edv[8];
#pragma unroll
            for (int e = 0; e < 8; e++) edv[e] = E[(hl * 2 + 1) * 64 + j8 + e];

#pragma unroll
            for (int mf = 0; mf < 4; mf++) {
                unsigned int mb = (unsigned int)(msk[mf] >> j8) & 0xffu;
                bf16x8 ph, pl;
                float rsum = 0.f;
#pragma unroll
                for (int e = 0; e < 8; e++) {
                    float t = leaky(esi[mf] + edv[e]);
                    float p = ((mb >> e) & 1u) ? __expf(t - mh[mf]) : 0.f;
                    rsum += p;
                    __bf16 hb = (__bf16)p;
                    ph[e] = hb;
                    pl[e] = (__bf16)(p - (float)hb);
                }
                rs[mf] += rsum;
#pragma unroll
                for (int nf2 = 0; nf2 < 2; nf2++) {
                    pv[mf][nf2] = MFMA16(ph, vh[nf2], pv[mf][nf2]);
                    pv[mf][nf2] = MFMA16(ph, vl[nf2], pv[mf][nf2]);
                    pv[mf][nf2] = MFMA16(pl, vh[nf2], pv[mf][nf2]);
                }
            }
        }

        // row sums -> 1/s
#pragma unroll
        for (int mf = 0; mf < 4; mf++) {
            float r = rs[mf];
            r += __shfl_xor(r, 16);
            r += __shfl_xor(r, 32);
            if (q == 0) invv[mf * 16 + d15] = (r > 0.f) ? 1.f / r : 0.f;
        }

        // epilogue: scale, residual (hi+lo), ELU, re-split store
#pragma unroll
        for (int mf = 0; mf < 4; mf++) {
#pragma unroll
            for (int nf2 = 0; nf2 < 2; nf2++) {
                int d = head * 32 + nf2 * 16 + d15;
#pragma unroll
                for (int rr = 0; rr < 4; rr++) {
                    int i = mf * 16 + q * 4 + rr;
                    float inv = invv[i];
                    size_t idx = (m0 + i) * 256 + d;
                    float old = (float)hhi[idx] + (float)hlo[idx];
                    float o = pv[mf][nf2][rr] * inv + old;
                    o = o > 0.f ? o : __expf(o) - 1.f;
                    __bf16 hb = (__bf16)o;
                    hhi[idx] = hb;
                    hlo[idx] = (__bf16)(o - (float)hb);
                }
            }
        }
    }
}

// ---------------------------------------------------------------------------
// Masked mean-pool + 3-layer MLP + elu + 1.5. One block per graph.
// ---------------------------------------------------------------------------
__global__ __launch_bounds__(256)
void pool_mlp(const unsigned long long* __restrict__ masks,
              const __bf16* __restrict__ hhi, const __bf16* __restrict__ hlo,
              const float* __restrict__ W1, const float* __restrict__ b1,
              const float* __restrict__ W2, const float* __restrict__ b2,
              const float* __restrict__ W3, const float* __restrict__ b3,
              float* __restrict__ out)
{
    __shared__ float lds_g[256];
    __shared__ float lds_z1[128];
    __shared__ float lds_z2[128];
    __shared__ unsigned long long lds_m;
    __shared__ float lds_invcnt;

    const int tid = threadIdx.x;
    const int b   = blockIdx.x;
    const __bf16* hbh = hhi + (size_t)b * 16384;
    const __bf16* hbl = hlo + (size_t)b * 16384;

    if (tid < 64) {
        unsigned long long rowm = masks[b * 64 + tid];
        unsigned long long m = __ballot((rowm >> tid) & 1ULL);
        if (tid == 0) { lds_m = m; lds_invcnt = 1.f / (float)__popcll(m); }
    }
    __syncthreads();

    unsigned long long msk = lds_m;
    float invc = lds_invcnt;
    float gsum = 0.f;
    for (int n = 0; n < 64; n++)
        if ((msk >> n) & 1ULL)
            gsum += (float)hbh[n * 256 + tid] + (float)hbl[n * 256 + tid];
    lds_g[tid] = gsum * invc;
    __syncthreads();

    if (tid < 128) {
        const float* wr = W1 + tid * 256;
        float z = 0.f;
#pragma unroll 8
        for (int k = 0; k < 256; k += 4) {
            float4 wv = *(const float4*)&wr[k];
            z += wv.x * lds_g[k] + wv.y * lds_g[k + 1] + wv.z * lds_g[k + 2] + wv.w * lds_g[k + 3];
        }
        z += b1[tid];
        lds_z1[tid] = z > 0.f ? z : 0.f;
    }
    __syncthreads();

    if (tid < 128) {
        const float* wr = W2 + tid * 128;
        float z = 0.f;
#pragma unroll 8
        for (int k = 0; k < 128; k += 4) {
            float4 wv = *(const float4*)&wr[k];
            z += wv.x * lds_z1[k] + wv.y * lds_z1[k + 1] + wv.z * lds_z1[k + 2] + wv.w * lds_z1[k + 3];
        }
        z += b2[tid];
        lds_z2[tid] = z > 0.f ? z : 0.f;
    }
    __syncthreads();

    if (tid < 64) {
        float p = W3[tid] * lds_z2[tid] + W3[tid + 64] * lds_z2[tid + 64];
        for (int off = 32; off; off >>= 1) p += __shfl_down(p, off);
        if (tid == 0) {
            float z = p + b3[0];
            out[b] = (z > 0.f ? z : __expf(z) - 1.f) + 1.5f;
        }
    }
}

// ---------------------------------------------------------------------------
extern "C" void kernel_launch(void* const* d_in, const int* in_sizes, int n_in,
                              void* d_out, int out_size, void* d_ws, size_t ws_size,
                              hipStream_t stream)
{
    const float* x      = (const float*)d_in[0];
    const float* A      = (const float*)d_in[1];
    const float* W_emb  = (const float*)d_in[2];
    const float* gat_W  = (const float*)d_in[3];
    const float* gat_b  = (const float*)d_in[4];
    const float* gat_a  = (const float*)d_in[5];
    const float* fc_W1  = (const float*)d_in[6];
    const float* fc_b1  = (const float*)d_in[7];
    const float* fc_W2  = (const float*)d_in[8];
    const float* fc_b2  = (const float*)d_in[9];
    const float* fc_W3  = (const float*)d_in[10];
    const float* fc_b3  = (const float*)d_in[11];
    float* out = (float*)d_out;

    // workspace (~171 MB):
    //   hhi bf16 [131072][256]      @ 0            67108864
    //   hlo bf16 [131072][256]      @ 67108864     67108864
    //   xhi/xlo bf16 [131072][64]   @ 134217728    2 x 16777216
    //   Whi_emb/Wlo_emb [256][64]   @ 167772160    2 x 32768
    //   Whi [6][272][256] bf16      @ 167837696    835584
    //   Wlo                         @ 168673280    835584
    //   ba  [6][16] f32             @ 169508864    384
    //   masks u64 [2048][64]        @ 169510912    1048576
    char* ws = (char*)d_ws;
    __bf16* hhi     = (__bf16*)ws;
    __bf16* hlo     = (__bf16*)(ws + 67108864);
    __bf16* xhi     = (__bf16*)(ws + 134217728);
    __bf16* xlo     = (__bf16*)(ws + 134217728 + 16777216);
    __bf16* Whi_emb = (__bf16*)(ws + 167772160);
    __bf16* Wlo_emb = (__bf16*)(ws + 167772160 + 32768);
    __bf16* Whi     = (__bf16*)(ws + 167837696);
    __bf16* Wlo     = (__bf16*)(ws + 168673280);
    float*  ba      = (float*)(ws + 169508864);
    unsigned long long* masks = (unsigned long long*)(ws + 169510912);

    int conv_total = L_LAYERS * 65536 + L_LAYERS * 4096 + L_LAYERS * 16;
    convert_weights<<<(conv_total + 255) / 256, 256, 0, stream>>>(
        W_emb, gat_W, gat_a, gat_b, Whi_emb, Wlo_emb, Whi, Wlo, ba);
    convert_x<<<M_FULL * 64 / 256, 256, 0, stream>>>(x, xhi, xlo);
    build_masks<<<B_GRAPHS, 256, 0, stream>>>(A, masks);

    gemm_embed<<<dim3(M_FULL / 128, 2), 256, 0, stream>>>(
        xhi, xlo, Whi_emb, Wlo_emb, hhi, hlo);

    for (int l = 0; l < L_LAYERS; l++) {
        fused_gat_layer<<<B_GRAPHS, 256, 0, stream>>>(
            masks, hhi, hlo,
            Whi + (size_t)l * WSLAB, Wlo + (size_t)l * WSLAB,
            gat_b + l * D_DIM, ba + l * 16);
    }

    pool_mlp<<<B_GRAPHS, 256, 0, stream>>>(masks, hhi, hlo, fc_W1, fc_b1,
                                           fc_W2, fc_b2, fc_W3, fc_b3, out);
}